// Round 8
// baseline (431.987 us; speedup 1.0000x reference)
//
#include <hip/hip_runtime.h>
#include <hip/hip_bf16.h>

#define NBLK 8
#define DIN 512
#define DOUT 512
#define NFEAT 4096      // NBLK * DIN
#define BATCH 8192
#define NT 16           // DIN / 32 K-steps
#define BM 256
#define BN 512

typedef __attribute__((ext_vector_type(8))) short short8;
typedef __attribute__((ext_vector_type(4))) float f32x4;

static __device__ __forceinline__ short f2bf16(float f) {
  __bf16 h = (__bf16)f;               // RNE; compiler packs into v_cvt_pk_bf16_f32
  return __builtin_bit_cast(short, h);
}

static __device__ __forceinline__ short8 cvt8(f32x4 lo, f32x4 hi) {
  short8 o;
  o[0] = f2bf16(lo[0]); o[1] = f2bf16(lo[1]); o[2] = f2bf16(lo[2]); o[3] = f2bf16(lo[3]);
  o[4] = f2bf16(hi[0]); o[5] = f2bf16(hi[1]); o[6] = f2bf16(hi[2]); o[7] = f2bf16(hi[3]);
  return o;
}

static __device__ __forceinline__ void gload_lds16(const void* g, void* l) {
  __builtin_amdgcn_global_load_lds(
      (const __attribute__((address_space(1))) void*)g,
      (__attribute__((address_space(3))) void*)l, 16, 0, 0);
}

// Pre-pass: W [8][512][512] fp32 -> Wp fragment-major bf16. Chunk (nb,cb,t)
// is 1 KB contiguous: lane l holds col cb*16+(l&15), k = t*32+(l>>4)*8.
__global__ __launch_bounds__(256) void wprep_kernel(const float* __restrict__ W,
                                                    short* __restrict__ Wp) {
  const int gid  = blockIdx.x * 256 + threadIdx.x;
  const int lane = gid & 63;
  const int t    = (gid >> 6) & 15;
  const int cb   = (gid >> 10) & 31;
  const int nb   = gid >> 15;
  const int col  = cb * 16 + (lane & 15);
  const int k    = t * 32 + (lane >> 4) * 8;
  const float* src = W + (size_t)(nb * DOUT + col) * DIN + k;
  f32x4 lo = *(const f32x4*)src;
  f32x4 hi = *(const f32x4*)(src + 4);
  *(short8*)(Wp + (size_t)gid * 8) = cvt8(lo, hi);
}

// Main: 256x512 block (x read EXACTLY ONCE chip-wide), 1024 threads,
// 16 waves = 4 M x 4 N, wave tile 64x128 (4x8 frags, 32 MFMA/step).
// A (x fp32): 3-buf LDS (96 KB), distance-2 (L3/HBM latency).
// B (Wp bf16): 2-buf LDS (64 KB), distance-1 (L2-hot slice).
// Counted vmcnt(2) steady (only A(t+2) in flight past the wait), one barrier
// per step, stage-after-barrier (race-free by the 3-buf/2-buf argument).
// Epilogue: per-wave LDS transpose -> full-line dwordx4 y stores.
template <bool WPREP>
__global__ __launch_bounds__(1024, 1) void blocklinear_kernel(
    const float* __restrict__ x, const float* __restrict__ W,
    const short* __restrict__ Wp, const float* __restrict__ bias,
    float* __restrict__ y)
{
  // nb = XCD id (grid 256, round-robin b%8 -> XCD): Wp slice (512 KB) L2-hot.
  const int b  = blockIdx.x;
  const int nb = b & 7;
  const int mt = b >> 3;       // 0..31

  const int tid  = threadIdx.x;
  const int lane = tid & 63;
  const int w    = tid >> 6;   // wave 0..15
  const int wr   = w >> 2;     // M-row 0..3 (rows wr*64..+64)
  const int wn   = w & 3;      // N-quarter 0..3 (cols wn*128..+128)
  const int l15  = lane & 15;
  const int k16  = lane >> 4;

  // 160 KiB exactly: A 3 x 32 KB + B 2 x 32 KB
  __shared__ __align__(16) char ldsraw[163840];
  float* Abase = (float*)ldsraw;                  // 3 * 8192 floats
  short* Bbase = (short*)(ldsraw + 98304);        // 2 * 16384 shorts

  // --- A staging: 32 x 1KB DMA instrs (256 rows x 128 B); wave w does 2:
  // rows w*16 + i*8 + (l>>3). dest chunk l&7 linear; source chunk pre-XOR'd
  // (l&7)^(l>>3): stored slot s of row r = data chunk s^(r&7).
  const int l8 = lane >> 3;
  const int c  = lane & 7;
  const float* asrc[2];
#pragma unroll
  for (int i = 0; i < 2; ++i) {
    const int gr = mt * BM + w * 16 + i * 8 + l8;
    asrc[i] = x + (size_t)gr * NFEAT + nb * DIN + ((c ^ l8) << 2);
  }
  // --- B staging: 32 x 1KB chunks (one per 16-col frag cb); wave w does 2.
  const short* bsrc[2];
#pragma unroll
  for (int i = 0; i < 2; ++i) {
    const int cb = w * 2 + i;
    bsrc[i] = WPREP ? Wp + ((size_t)(nb * 32 + cb) * 16) * 512 + lane * 8 : nullptr;
  }

#define STAGE_A(buf, t)                                                     \
  {                                                                         \
    _Pragma("unroll")                                                       \
    for (int i = 0; i < 2; ++i)                                             \
      gload_lds16(asrc[i] + (t) * 32, Abase + (buf) * 8192 + (w * 16 + i * 8) * 32); \
  }
#define STAGE_B(buf, t)                                                     \
  {                                                                         \
    if constexpr (WPREP) {                                                  \
      _Pragma("unroll")                                                     \
      for (int i = 0; i < 2; ++i)                                           \
        gload_lds16(bsrc[i] + (t) * 512, Bbase + (buf) * 16384 + (w * 2 + i) * 512); \
    }                                                                       \
  }

  // --- A fragment read offsets: row = wr*64 + m*16 + l15 (row&7 == l15&7),
  // addr = row*32 + slot*4, slot = (2k16 / 2k16+1) ^ (l15&7).
  const int ra_base = (wr * 64 + l15) * 32;
  const int ra_lo   = ra_base + (((2 * k16)     ^ (l15 & 7)) << 2);
  const int ra_hi   = ra_base + (((2 * k16 + 1) ^ (l15 & 7)) << 2);

  f32x4 acc[4][8];
#pragma unroll
  for (int m = 0; m < 4; ++m)
#pragma unroll
    for (int n = 0; n < 8; ++n)
      acc[m][n] = (f32x4){0.f, 0.f, 0.f, 0.f};

#define COMPUTE(abuf, bbuf)                                                 \
  {                                                                         \
    const float* la = Abase + (abuf) * 8192;                                \
    const short* lb = Bbase + (bbuf) * 16384;                               \
    short8 af[4], bf[8];                                                    \
    _Pragma("unroll")                                                       \
    for (int m = 0; m < 4; ++m) {                                           \
      f32x4 lo = *(const f32x4*)(la + m * 512 + ra_lo);                     \
      f32x4 hi = *(const f32x4*)(la + m * 512 + ra_hi);                     \
      af[m] = cvt8(lo, hi);                                                 \
    }                                                                       \
    if constexpr (WPREP) {                                                  \
      _Pragma("unroll")                                                     \
      for (int n = 0; n < 8; ++n)                                           \
        bf[n] = *(const short8*)(lb + (wn * 8 + n) * 512 + lane * 8);       \
    } else {                                                                \
      _Pragma("unroll")                                                     \
      for (int n = 0; n < 8; ++n) {                                         \
        const int col = wn * 128 + n * 16 + l15;                            \
        const float* bp = W + (size_t)nb * DOUT * DIN + (size_t)col * DIN + \
                          CUR_T * 32 + k16 * 8;                             \
        bf[n] = cvt8(*(const f32x4*)bp, *(const f32x4*)(bp + 4));           \
      }                                                                     \
    }                                                                       \
    __builtin_amdgcn_s_setprio(1);                                          \
    _Pragma("unroll")                                                       \
    for (int m = 0; m < 4; ++m)                                             \
      _Pragma("unroll")                                                     \
      for (int n = 0; n < 8; ++n)                                           \
        acc[m][n] = __builtin_amdgcn_mfma_f32_16x16x32_bf16(af[m], bf[n], acc[m][n], 0, 0, 0); \
    __builtin_amdgcn_s_setprio(0);                                          \
  }

  // Step t: wait A(t),B(t) landed (in-order queue: leaves only A(t+2-? ) ->
  // vmcnt(2)); barrier (stages visible block-wide); issue B(t+1) then A(t+2)
  // into buffers last read at t-1 (race-free); compute(t).
#define STEP(t, VMC)                                                        \
  {                                                                         \
    constexpr int CUR_T = (t);                                              \
    (void)CUR_T;                                                            \
    __builtin_amdgcn_sched_barrier(0);                                      \
    asm volatile("s_waitcnt vmcnt(" #VMC ")" ::: "memory");                 \
    __builtin_amdgcn_s_barrier();                                           \
    __builtin_amdgcn_sched_barrier(0);                                      \
    if ((t) + 1 < NT) STAGE_B((t + 1) & 1, (t) + 1);                        \
    if ((t) + 2 < NT) STAGE_A(((t) + 2) % 3, (t) + 2);                      \
    COMPUTE((t) % 3, (t) & 1);                                              \
  }

  // prologue: B(0), A(0), A(1) (issue order matters for the vmcnt counts)
  STAGE_B(0, 0);
  STAGE_A(0, 0);
  STAGE_A(1, 1);

  if constexpr (WPREP) {
    STEP(0, 2)  STEP(1, 2)  STEP(2, 2)  STEP(3, 2)
    STEP(4, 2)  STEP(5, 2)  STEP(6, 2)  STEP(7, 2)
    STEP(8, 2)  STEP(9, 2)  STEP(10, 2) STEP(11, 2)
    STEP(12, 2) STEP(13, 2) STEP(14, 2) STEP(15, 0)
  } else {
    STEP(0, 0)  STEP(1, 0)  STEP(2, 0)  STEP(3, 0)
    STEP(4, 0)  STEP(5, 0)  STEP(6, 0)  STEP(7, 0)
    STEP(8, 0)  STEP(9, 0)  STEP(10, 0) STEP(11, 0)
    STEP(12, 0) STEP(13, 0) STEP(14, 0) STEP(15, 0)
  }

  // ---- Epilogue: per-wave LDS transpose -> full-line coalesced y stores.
  // bias per lane (8 cols)
  float bv[8];
#pragma unroll
  for (int n = 0; n < 8; ++n)
    bv[n] = bias[nb * DOUT + wn * 128 + n * 16 + l15];

  __builtin_amdgcn_s_barrier();            // all K-loop LDS reads done
  float* scr = (float*)ldsraw + w * 2048;  // private 8 KB slice per wave

#pragma unroll
  for (int m = 0; m < 4; ++m) {
    // scatter acc sub-tile (16 rows x 128 cols) into scratch
#pragma unroll
    for (int n = 0; n < 8; ++n)
#pragma unroll
      for (int j = 0; j < 4; ++j)
        scr[(k16 * 4 + j) * 128 + n * 16 + l15] = acc[m][n][j] + bv[n];
    // gather coalesced: lane -> rows i*2+(lane>>5), 16B col chunk
#pragma unroll
    for (int i = 0; i < 8; ++i) {
      f32x4 v = *(const f32x4*)(scr + i * 256 + lane * 4);
      const int row = mt * BM + wr * 64 + m * 16 + i * 2 + (lane >> 5);
      float* yp = y + (size_t)row * NFEAT + nb * DIN + wn * 128 + (lane & 31) * 4;
      *(f32x4*)yp = v;
    }
    // next m reuses scratch: in-wave ds order is handled by compiler waits
  }
}

extern "C" void kernel_launch(void* const* d_in, const int* in_sizes, int n_in,
                              void* d_out, int out_size, void* d_ws, size_t ws_size,
                              hipStream_t stream) {
  const float* x  = (const float*)d_in[0];
  const float* W  = (const float*)d_in[1];
  const float* bi = (const float*)d_in[2];
  float* y = (float*)d_out;
  const size_t wp_bytes = (size_t)NBLK * DOUT * DIN * sizeof(short);  // 4 MiB
  const int grid = NBLK * (BATCH / BM) * (DOUT / BN);                 // 256

  if (ws_size >= wp_bytes) {
    short* Wp = (short*)d_ws;
    wprep_kernel<<<(NBLK * DOUT * DIN / 8) / 256, 256, 0, stream>>>(W, Wp);
    blocklinear_kernel<true><<<grid, 1024, 0, stream>>>(x, W, Wp, bi, y);
  } else {
    blocklinear_kernel<false><<<grid, 1024, 0, stream>>>(x, W, nullptr, bi, y);
  }
}

// Round 9
// 145.508 us; speedup vs baseline: 2.9688x; 2.9688x over previous
//
#include <hip/hip_runtime.h>
#include <hip/hip_bf16.h>

#define NBLK 8
#define DIN 512
#define DOUT 512
#define NFEAT 4096      // NBLK * DIN
#define BATCH 8192
#define NT 16           // DIN / 32 K-steps
#define BM 256
#define BN 256          // per nt-pass; each block covers both halves of DOUT

typedef __attribute__((ext_vector_type(8))) short short8;
typedef __attribute__((ext_vector_type(4))) float f32x4;

static __device__ __forceinline__ short f2bf16(float f) {
  __bf16 h = (__bf16)f;               // RNE; compiler packs into v_cvt_pk_bf16_f32
  return __builtin_bit_cast(short, h);
}

static __device__ __forceinline__ short8 cvt8(f32x4 lo, f32x4 hi) {
  short8 o;
  o[0] = f2bf16(lo[0]); o[1] = f2bf16(lo[1]); o[2] = f2bf16(lo[2]); o[3] = f2bf16(lo[3]);
  o[4] = f2bf16(hi[0]); o[5] = f2bf16(hi[1]); o[6] = f2bf16(hi[2]); o[7] = f2bf16(hi[3]);
  return o;
}

static __device__ __forceinline__ void gload_lds16(const void* g, void* l) {
  __builtin_amdgcn_global_load_lds(
      (const __attribute__((address_space(1))) void*)g,
      (__attribute__((address_space(3))) void*)l, 16, 0, 0);
}

// Pre-pass: W [8][512][512] fp32 -> Wp fragment-major bf16. Chunk (nb,cb,t)
// is 1 KB contiguous: lane l holds col cb*16+(l&15), k = t*32+(l>>4)*8.
__global__ __launch_bounds__(256) void wprep_kernel(const float* __restrict__ W,
                                                    short* __restrict__ Wp) {
  const int gid  = blockIdx.x * 256 + threadIdx.x;
  const int lane = gid & 63;
  const int t    = (gid >> 6) & 15;
  const int cb   = (gid >> 10) & 31;
  const int nb   = gid >> 15;
  const int col  = cb * 16 + (lane & 15);
  const int k    = t * 32 + (lane >> 4) * 8;
  const float* src = W + (size_t)(nb * DOUT + col) * DIN + k;
  f32x4 lo = *(const f32x4*)src;
  f32x4 hi = *(const f32x4*)(src + 4);
  *(short8*)(Wp + (size_t)gid * 8) = cvt8(lo, hi);
}

// Main: grid 256 = 1 block/CU, nb = b&7 = XCD id. Each block: 256 x-rows,
// BOTH 256-col halves of its nb's DOUT, sequentially (nt=0,1) -> x leaves
// HBM/L3 once; the nt=1 re-read hits warm cache. 512 threads, 8 waves
// (4 M-rows x 2 N-halves), wave tile 64x128, R7's proven pipeline:
// A+B staged distance-2 via global_load_lds into 3 buffers, vmcnt(6)
// counted (never drained mid-loop), one barrier per step.
// Epilogue: per-wave padded LDS transpose -> dwordx4 512-B store runs.
template <bool WPREP>
__global__ __launch_bounds__(512, 2) void blocklinear_kernel(
    const float* __restrict__ x, const float* __restrict__ W,
    const short* __restrict__ Wp, const float* __restrict__ bias,
    float* __restrict__ y)
{
  const int b  = blockIdx.x;
  const int nb = b & 7;        // XCD id: Wp slice (512 KB) stays L2-hot
  const int mt = b >> 3;       // 0..31

  const int tid  = threadIdx.x;
  const int lane = tid & 63;
  const int w    = tid >> 6;   // wave 0..7
  const int wr   = w >> 1;     // M-row 0..3 (rows wr*64..+64)
  const int hN   = w & 1;      // N-half within the 256-col pass
  const int l15  = lane & 15;
  const int k16  = lane >> 4;

  __shared__ __align__(16) float Abuf[3][8192];   // 3 x 32 KB (fp32 A tiles)
  __shared__ __align__(16) short Bbuf[3][8192];   // 3 x 16 KB (bf16 B tiles)

  // --- A staging: 32 x 1KB DMAs cover 256 rows x 128 B; wave w does 4.
  // lane l -> row +(l>>3), dest chunk l&7 (linear); source chunk pre-XOR'd
  // (l&7)^(l>>3): stored slot s of row r holds data chunk s^(r&7).
  const int l8 = lane >> 3;
  const int c  = lane & 7;
  const float* asrc[4];
#pragma unroll
  for (int i = 0; i < 4; ++i) {
    const int gr = mt * BM + w * 32 + i * 8 + l8;
    asrc[i] = x + (size_t)gr * NFEAT + nb * DIN + ((c ^ l8) << 2);
  }

  // --- A fragment read offsets: row = wr*64 + m*16 + l15 (row&7 == l15&7),
  // addr = row*32 + slot*4, slot = (2k16 / 2k16+1) ^ (l15&7).
  const int ra_base = (wr * 64 + l15) * 32;
  const int ra_lo   = ra_base + (((2 * k16)     ^ (l15 & 7)) << 2);
  const int ra_hi   = ra_base + (((2 * k16 + 1) ^ (l15 & 7)) << 2);

#define STAGE(buf, t)                                                       \
  {                                                                         \
    _Pragma("unroll")                                                       \
    for (int i = 0; i < 4; ++i)                                             \
      gload_lds16(asrc[i] + (t) * 32, &Abuf[buf][(w * 32 + i * 8) * 32]);   \
    if constexpr (WPREP) {                                                  \
      gload_lds16(bsrc0 + (t) * 512, &Bbuf[buf][(w * 2) * 512]);            \
      gload_lds16(bsrc1 + (t) * 512, &Bbuf[buf][(w * 2 + 1) * 512]);        \
    }                                                                       \
  }

#define COMPUTE(buf)                                                        \
  {                                                                         \
    const float* la = &Abuf[buf][0];                                        \
    const short* lb = &Bbuf[buf][0];                                        \
    short8 af[4], bf[8];                                                    \
    _Pragma("unroll")                                                       \
    for (int m = 0; m < 4; ++m) {                                           \
      f32x4 lo = *(const f32x4*)(la + m * 512 + ra_lo);                     \
      f32x4 hi = *(const f32x4*)(la + m * 512 + ra_hi);                     \
      af[m] = cvt8(lo, hi);                                                 \
    }                                                                       \
    if constexpr (WPREP) {                                                  \
      _Pragma("unroll")                                                     \
      for (int n = 0; n < 8; ++n)                                           \
        bf[n] = *(const short8*)(lb + (hN * 8 + n) * 512 + lane * 8);       \
    } else {                                                                \
      _Pragma("unroll")                                                     \
      for (int n = 0; n < 8; ++n) {                                         \
        const int col = nt * BN + hN * 128 + n * 16 + l15;                  \
        const float* bp = W + (size_t)nb * DOUT * DIN + (size_t)col * DIN + \
                          CUR_T * 32 + k16 * 8;                             \
        bf[n] = cvt8(*(const f32x4*)bp, *(const f32x4*)(bp + 4));           \
      }                                                                     \
    }                                                                       \
    __builtin_amdgcn_s_setprio(1);                                          \
    _Pragma("unroll")                                                       \
    for (int m = 0; m < 4; ++m)                                             \
      _Pragma("unroll")                                                     \
      for (int n = 0; n < 8; ++n)                                           \
        acc[m][n] = __builtin_amdgcn_mfma_f32_16x16x32_bf16(af[m], bf[n], acc[m][n], 0, 0, 0); \
    __builtin_amdgcn_s_setprio(0);                                          \
  }

  // Step t: wait t's 6 stages landed (t+1's 6 stay in flight -> vmcnt(6));
  // barrier; stage t+2 into the buffer all waves finished reading at t-1;
  // compute t.
#define STEP(t, VMC)                                                        \
  {                                                                         \
    const int CUR_T = (t);                                                  \
    (void)CUR_T;                                                            \
    __builtin_amdgcn_sched_barrier(0);                                      \
    asm volatile("s_waitcnt vmcnt(" #VMC ")" ::: "memory");                 \
    __builtin_amdgcn_s_barrier();                                           \
    __builtin_amdgcn_sched_barrier(0);                                      \
    if ((t) + 2 < NT) STAGE(((t) + 2) % 3, (t) + 2);                        \
    COMPUTE((t) % 3);                                                       \
  }

  auto run_tile = [&](const int nt) {
    // B sources for this 256-col half (cb = nt*16 + w*2 + i)
    const short* bsrc0 = WPREP
        ? Wp + ((size_t)(nb * 32 + nt * 16 + w * 2) * 16) * 512 + lane * 8
        : nullptr;
    const short* bsrc1 = WPREP ? bsrc0 + (size_t)16 * 512 : nullptr;

    f32x4 acc[4][8];
#pragma unroll
    for (int m = 0; m < 4; ++m)
#pragma unroll
      for (int n = 0; n < 8; ++n)
        acc[m][n] = (f32x4){0.f, 0.f, 0.f, 0.f};

    // protect LDS from the previous pass's epilogue readers
    __builtin_amdgcn_s_barrier();

    STAGE(0, 0);
    STAGE(1, 1);

    if constexpr (WPREP) {
      STEP(0, 6)  STEP(1, 6)  STEP(2, 6)  STEP(3, 6)
      STEP(4, 6)  STEP(5, 6)  STEP(6, 6)  STEP(7, 6)
      STEP(8, 6)  STEP(9, 6)  STEP(10, 6) STEP(11, 6)
      STEP(12, 6) STEP(13, 6) STEP(14, 6) STEP(15, 0)
    } else {
      STEP(0, 0)  STEP(1, 0)  STEP(2, 0)  STEP(3, 0)
      STEP(4, 0)  STEP(5, 0)  STEP(6, 0)  STEP(7, 0)
      STEP(8, 0)  STEP(9, 0)  STEP(10, 0) STEP(11, 0)
      STEP(12, 0) STEP(13, 0) STEP(14, 0) STEP(15, 0)
    }

    // ---- Epilogue: per-wave padded LDS transpose -> 512-B dwordx4 runs.
    float bv[8];
#pragma unroll
    for (int n = 0; n < 8; ++n)
      bv[n] = bias[nb * DOUT + nt * BN + hN * 128 + n * 16 + l15];

    __builtin_amdgcn_s_barrier();              // all K-loop LDS reads done
    float* scr = &Abuf[0][0] + w * 2112;       // 16 rows x 132 (padded), private

#pragma unroll
    for (int m = 0; m < 4; ++m) {
      // scatter 16x128 sub-tile; stride 132 -> worst 2-way bank conflict
#pragma unroll
      for (int n = 0; n < 8; ++n)
#pragma unroll
        for (int j = 0; j < 4; ++j)
          scr[(k16 * 4 + j) * 132 + n * 16 + l15] = acc[m][n][j] + bv[n];
      // gather coalesced: lanes 0-31 / 32-63 cover two full 512-B row runs
#pragma unroll
      for (int i = 0; i < 8; ++i) {
        f32x4 v = *(const f32x4*)(scr + i * 264 + (lane >> 5) * 132 + (lane & 31) * 4);
        const int row = mt * BM + wr * 64 + m * 16 + i * 2 + (lane >> 5);
        float* yp = y + (size_t)row * NFEAT + nb * DIN + nt * BN + hN * 128 + (lane & 31) * 4;
        *(f32x4*)yp = v;
      }
    }
  };

  run_tile(0);
  run_tile(1);
}

extern "C" void kernel_launch(void* const* d_in, const int* in_sizes, int n_in,
                              void* d_out, int out_size, void* d_ws, size_t ws_size,
                              hipStream_t stream) {
  const float* x  = (const float*)d_in[0];
  const float* W  = (const float*)d_in[1];
  const float* bi = (const float*)d_in[2];
  float* y = (float*)d_out;
  const size_t wp_bytes = (size_t)NBLK * DOUT * DIN * sizeof(short);  // 4 MiB
  const int grid = NBLK * (BATCH / BM);                               // 256

  if (ws_size >= wp_bytes) {
    short* Wp = (short*)d_ws;
    wprep_kernel<<<(NBLK * DOUT * DIN / 8) / 256, 256, 0, stream>>>(W, Wp);
    blocklinear_kernel<true><<<grid, 512, 0, stream>>>(x, W, Wp, bi, y);
  } else {
    blocklinear_kernel<false><<<grid, 512, 0, stream>>>(x, W, nullptr, bi, y);
  }
}

// Round 10
// 81.293 us; speedup vs baseline: 5.3139x; 1.7899x over previous
//
#include <hip/hip_runtime.h>
#include <hip/hip_bf16.h>

#define NBLK 8
#define DIN 512
#define DOUT 512
#define NFEAT 4096      // NBLK * DIN
#define BATCH 8192
#define NT 16           // DIN / 32 K-steps
#define BM 256
#define BN 256

typedef __attribute__((ext_vector_type(8))) short short8;
typedef __attribute__((ext_vector_type(4))) float f32x4;

static __device__ __forceinline__ short f2bf16(float f) {
  __bf16 h = (__bf16)f;               // RNE; compiler packs into v_cvt_pk_bf16_f32
  return __builtin_bit_cast(short, h);
}

static __device__ __forceinline__ short8 cvt8(f32x4 lo, f32x4 hi) {
  short8 o;
  o[0] = f2bf16(lo[0]); o[1] = f2bf16(lo[1]); o[2] = f2bf16(lo[2]); o[3] = f2bf16(lo[3]);
  o[4] = f2bf16(hi[0]); o[5] = f2bf16(hi[1]); o[6] = f2bf16(hi[2]); o[7] = f2bf16(hi[3]);
  return o;
}

static __device__ __forceinline__ void gload_lds16(const void* g, void* l) {
  __builtin_amdgcn_global_load_lds(
      (const __attribute__((address_space(1))) void*)g,
      (__attribute__((address_space(3))) void*)l, 16, 0, 0);
}

// Pre-pass: W [8][512][512] fp32 -> Wp fragment-major bf16. Chunk (nb,cb,t)
// is 1 KB contiguous: lane l holds col cb*16+(l&15), k = t*32+(l>>4)*8.
__global__ __launch_bounds__(256) void wprep_kernel(const float* __restrict__ W,
                                                    short* __restrict__ Wp) {
  const int gid  = blockIdx.x * 256 + threadIdx.x;
  const int lane = gid & 63;
  const int t    = (gid >> 6) & 15;
  const int cb   = (gid >> 10) & 31;
  const int nb   = gid >> 15;
  const int col  = cb * 16 + (lane & 15);
  const int k    = t * 32 + (lane >> 4) * 8;
  const float* src = W + (size_t)(nb * DOUT + col) * DIN + k;
  f32x4 lo = *(const f32x4*)src;
  f32x4 hi = *(const f32x4*)(src + 4);
  *(short8*)(Wp + (size_t)gid * 8) = cvt8(lo, hi);
}

// Main (R7 structure, verified 77.4 us): 256x256 block, 512 threads, 8 waves
// = 4 M-rows x 2 N-halves, wave tile 64x128 (4x8 frags, 32 MFMA/step).
// A (x fp32) + B (Wp bf16) staged once per block per step via global_load_lds,
// 3 buffers each, distance-2, counted vmcnt(6) (never drained mid-loop),
// one barrier per step, stage-after-barrier (race-free: that buffer was last
// read at t-1, and every wave's t-1 ds_reads completed before its barrier).
// R10 diffs vs R7: (1) nontemporal y-stores (y is write-once; stop evicting
// the L3-resident x panels), (2) launch_bounds(512,1) frees the VGPR cap
// (LDS already limits to 1 block/CU, so no occupancy cost).
template <bool WPREP>
__global__ __launch_bounds__(512, 1) void blocklinear_kernel(
    const float* __restrict__ x, const float* __restrict__ W,
    const short* __restrict__ Wp, const float* __restrict__ bias,
    float* __restrict__ y)
{
  // XCD swizzle (bijective: 512 % 8 == 0): one nb per XCD, nt innermost
  // (2 nt-siblings share an x M-panel on one XCD's L2/L3 path).
  const int b       = blockIdx.x;
  const int logical = (b & 7) * 64 + (b >> 3);
  const int nb  = logical >> 6;
  const int rem = logical & 63;
  const int mt  = rem >> 1;    // 0..31
  const int nt  = rem & 1;     // 0..1

  const int tid  = threadIdx.x;
  const int lane = tid & 63;
  const int w    = tid >> 6;   // wave 0..7
  const int wr   = w >> 1;     // M-row 0..3 (rows wr*64..+64)
  const int hN   = w & 1;      // N-half 0..1 (cols hN*128..+128)
  const int l15  = lane & 15;
  const int k16  = lane >> 4;

  __shared__ __align__(16) float Abuf[3][BM * 32];   // 3 x 32 KB
  __shared__ __align__(16) short Bbuf[3][BN * 32];   // 3 x 16 KB  (144 KB total)

  // --- A staging: 32 x 1KB DMA instrs cover 256 rows; wave w does 4 (i=0..3),
  // rows w*32+i*8 .. +8. lane l -> row +(l>>3), dest chunk l&7 (linear);
  // source pre-swizzled chunk (l&7)^(l>>3): stored slot s = data chunk s^(row&7).
  const int l8 = lane >> 3;
  const int c  = lane & 7;
  const float* asrc[4];
#pragma unroll
  for (int i = 0; i < 4; ++i) {
    const int gr = mt * BM + w * 32 + i * 8 + l8;
    asrc[i] = x + (size_t)gr * NFEAT + nb * DIN + ((c ^ l8) << 2);
  }
  // --- B staging: 16 x 1KB chunks (one per 16-col frag); wave w does 2.
  const short* bsrc[2];
#pragma unroll
  for (int i = 0; i < 2; ++i) {
    const int cb = nt * 16 + w * 2 + i;
    bsrc[i] = WPREP ? Wp + ((size_t)(nb * 32 + cb) * 16) * 512 + lane * 8 : nullptr;
  }

#define STAGE(buf, t)                                                       \
  {                                                                         \
    _Pragma("unroll")                                                       \
    for (int i = 0; i < 4; ++i)                                             \
      gload_lds16(asrc[i] + (t) * 32, &Abuf[buf][(w * 32 + i * 8) * 32]);   \
    if constexpr (WPREP) {                                                  \
      _Pragma("unroll")                                                     \
      for (int i = 0; i < 2; ++i)                                           \
        gload_lds16(bsrc[i] + (t) * 512, &Bbuf[buf][(w * 2 + i) * 512]);    \
    }                                                                       \
  }

  // --- A fragment read offsets (floats): row_local = wr*64 + m*16 + l15,
  // addr = row_local*32 + slot*4, slot = (2k16 / 2k16+1) ^ (l15&7).
  const int ra_base = (wr * 64 + l15) * 32;
  const int ra_lo   = ra_base + (((2 * k16)     ^ (l15 & 7)) << 2);
  const int ra_hi   = ra_base + (((2 * k16 + 1) ^ (l15 & 7)) << 2);

  f32x4 acc[4][8];
#pragma unroll
  for (int m = 0; m < 4; ++m)
#pragma unroll
    for (int n = 0; n < 8; ++n)
      acc[m][n] = (f32x4){0.f, 0.f, 0.f, 0.f};

#define COMPUTE(buf)                                                        \
  {                                                                         \
    const float* la = &Abuf[buf][0];                                        \
    const short* lb = &Bbuf[buf][0];                                        \
    short8 af[4], bf[8];                                                    \
    _Pragma("unroll")                                                       \
    for (int m = 0; m < 4; ++m) {                                           \
      f32x4 lo = *(const f32x4*)(la + m * 512 + ra_lo);                     \
      f32x4 hi = *(const f32x4*)(la + m * 512 + ra_hi);                     \
      af[m] = cvt8(lo, hi);                                                 \
    }                                                                       \
    if constexpr (WPREP) {                                                  \
      _Pragma("unroll")                                                     \
      for (int n = 0; n < 8; ++n)                                           \
        bf[n] = *(const short8*)(lb + (hN * 8 + n) * 512 + lane * 8);       \
    } else {                                                                \
      _Pragma("unroll")                                                     \
      for (int n = 0; n < 8; ++n) {                                         \
        const int col = nt * BN + hN * 128 + n * 16 + l15;                  \
        const float* bp = W + (size_t)nb * DOUT * DIN + (size_t)col * DIN + \
                          CUR_T * 32 + k16 * 8;                             \
        bf[n] = cvt8(*(const f32x4*)bp, *(const f32x4*)(bp + 4));           \
      }                                                                     \
    }                                                                       \
    __builtin_amdgcn_s_setprio(1);                                          \
    _Pragma("unroll")                                                       \
    for (int m = 0; m < 4; ++m)                                             \
      _Pragma("unroll")                                                     \
      for (int n = 0; n < 8; ++n)                                           \
        acc[m][n] = __builtin_amdgcn_mfma_f32_16x16x32_bf16(af[m], bf[n], acc[m][n], 0, 0, 0); \
    __builtin_amdgcn_s_setprio(0);                                          \
  }

  // Step t: wait t's 6 stages landed (t+1's 6 stay in flight -> vmcnt(6));
  // barrier; stage t+2 into the buffer all waves finished reading at t-1;
  // compute t.
#define STEP(t, VMC)                                                        \
  {                                                                         \
    constexpr int CUR_T = (t);                                              \
    (void)CUR_T;                                                            \
    __builtin_amdgcn_sched_barrier(0);                                      \
    asm volatile("s_waitcnt vmcnt(" #VMC ")" ::: "memory");                 \
    __builtin_amdgcn_s_barrier();                                           \
    __builtin_amdgcn_sched_barrier(0);                                      \
    if ((t) + 2 < NT) STAGE(((t) + 2) % 3, (t) + 2);                        \
    COMPUTE((t) % 3);                                                       \
  }

  STAGE(0, 0);
  STAGE(1, 1);

  if constexpr (WPREP) {
    STEP(0, 6)  STEP(1, 6)  STEP(2, 6)  STEP(3, 6)
    STEP(4, 6)  STEP(5, 6)  STEP(6, 6)  STEP(7, 6)
    STEP(8, 6)  STEP(9, 6)  STEP(10, 6) STEP(11, 6)
    STEP(12, 6) STEP(13, 6) STEP(14, 6) STEP(15, 0)
  } else {
    STEP(0, 0)  STEP(1, 0)  STEP(2, 0)  STEP(3, 0)
    STEP(4, 0)  STEP(5, 0)  STEP(6, 0)  STEP(7, 0)
    STEP(8, 0)  STEP(9, 0)  STEP(10, 0) STEP(11, 0)
    STEP(12, 0) STEP(13, 0) STEP(14, 0) STEP(15, 0)
  }

  // epilogue (R7 pattern + nontemporal): C/D layout col = lane&15,
  // row = (lane>>4)*4 + j  [m89-verified]. y is write-once -> nt stores
  // keep L2/L3 free for the x panels.
  const int col0 = nt * BN + hN * 128;
  const int row0 = mt * BM + wr * 64;
  const float* bptr = bias + nb * DOUT + col0;
#pragma unroll
  for (int n = 0; n < 8; ++n) {
    const float bv = bptr[n * 16 + l15];
    const size_t col = (size_t)nb * DOUT + col0 + n * 16 + l15;
#pragma unroll
    for (int m = 0; m < 4; ++m) {
      const int row = row0 + m * 16 + k16 * 4;
      float* yp = y + (size_t)row * NFEAT + col;
#pragma unroll
      for (int j = 0; j < 4; ++j)
        __builtin_nontemporal_store(acc[m][n][j] + bv, yp + (size_t)j * NFEAT);
    }
  }
}

extern "C" void kernel_launch(void* const* d_in, const int* in_sizes, int n_in,
                              void* d_out, int out_size, void* d_ws, size_t ws_size,
                              hipStream_t stream) {
  const float* x  = (const float*)d_in[0];
  const float* W  = (const float*)d_in[1];
  const float* bi = (const float*)d_in[2];
  float* y = (float*)d_out;
  const size_t wp_bytes = (size_t)NBLK * DOUT * DIN * sizeof(short);  // 4 MiB
  const int grid = NBLK * (BATCH / BM) * (DOUT / BN);                 // 512

  if (ws_size >= wp_bytes) {
    short* Wp = (short*)d_ws;
    wprep_kernel<<<(NBLK * DOUT * DIN / 8) / 256, 256, 0, stream>>>(W, Wp);
    blocklinear_kernel<true><<<grid, 512, 0, stream>>>(x, W, Wp, bi, y);
  } else {
    blocklinear_kernel<false><<<grid, 512, 0, stream>>>(x, W, nullptr, bi, y);
  }
}